// Round 6
// baseline (3772.316 us; speedup 1.0000x reference)
//
#include <hip/hip_runtime.h>
#include <hip/hip_bf16.h>

// ---------------------------------------------------------------------------
// Problem constants (reference: B,N,T,P,H = 256,101,128,4,16)
// ---------------------------------------------------------------------------
constexpr int B = 256;
constexpr int N = 101;
constexpr int T = 128;

__device__ __forceinline__ float frcp(float x) { return __builtin_amdgcn_rcpf(x); }
__device__ __forceinline__ float sigmoidf_(float x) { return frcp(1.f + __expf(-x)); }
// tanh(x) = 2*sigmoid(2x) - 1  (safe at large |x|)
__device__ __forceinline__ float tanhf_(float x) { return 2.f * frcp(1.f + __expf(-2.f * x)) - 1.f; }

// ---------------------------------------------------------------------------
// K1: LSTM, 16 lanes per (b,n) row (lane = hidden unit). Weights in VGPRs.
// Recurrent h broadcast via __shfl. h_out: [B*N][16]
// ---------------------------------------------------------------------------
__global__ __launch_bounds__(256) void lstm_kernel(
    const float* __restrict__ x,     // [B][N][T][4]
    const float* __restrict__ pw,    // [4][4]
    const float* __restrict__ pb,    // [4]
    const float* __restrict__ w_ih,  // [64][4]
    const float* __restrict__ w_hh,  // [64][16]
    const float* __restrict__ b_ih,  // [64]
    const float* __restrict__ b_hh,  // [64]
    float* __restrict__ h_out) {
  const int tid = threadIdx.x;
  const int lane = tid & 63;
  const int sub = lane >> 4;   // row within wave (0..3)
  const int k = lane & 15;     // hidden unit owned by this lane
  const int wave = tid >> 6;   // wave within block (0..3)
  const int bn = blockIdx.x * 16 + wave * 4 + sub;  // 1616*16 = 25856 exact

  float wih[4][4], whh[4][16], bias[4];
#pragma unroll
  for (int q = 0; q < 4; q++) {
    const int j = q * 16 + k;  // gate order i,f,g,o
    bias[q] = b_ih[j] + b_hh[j];
#pragma unroll
    for (int jj = 0; jj < 4; jj++) wih[q][jj] = w_ih[j * 4 + jj];
#pragma unroll
    for (int m = 0; m < 16; m++) whh[q][m] = w_hh[j * 16 + m];
  }
  float pwr[16], pbr[4];
#pragma unroll
  for (int i = 0; i < 16; i++) pwr[i] = pw[i];
#pragma unroll
  for (int i = 0; i < 4; i++) pbr[i] = pb[i];

  float h = 0.f, c = 0.f;
  const float4* xp = (const float4*)x + (size_t)bn * T;
  const int base = sub * 16;

#pragma unroll 1
  for (int t = 0; t < T; t++) {
    float4 xr = xp[t];
    float xv[4];
#pragma unroll
    for (int j = 0; j < 4; j++)
      xv[j] = pbr[j] + pwr[j * 4 + 0] * xr.x + pwr[j * 4 + 1] * xr.y +
              pwr[j * 4 + 2] * xr.z + pwr[j * 4 + 3] * xr.w;
    float a0 = bias[0], a1 = bias[1], a2 = bias[2], a3 = bias[3];
#pragma unroll
    for (int j = 0; j < 4; j++) {
      a0 += wih[0][j] * xv[j];
      a1 += wih[1][j] * xv[j];
      a2 += wih[2][j] * xv[j];
      a3 += wih[3][j] * xv[j];
    }
#pragma unroll
    for (int m = 0; m < 16; m++) {
      float hm = __shfl(h, base + m, 64);
      a0 += whh[0][m] * hm;
      a1 += whh[1][m] * hm;
      a2 += whh[2][m] * hm;
      a3 += whh[3][m] * hm;
    }
    float ig = sigmoidf_(a0);
    float fg = sigmoidf_(a1);
    float gg = tanhf_(a2);
    float og = sigmoidf_(a3);
    c = fg * c + ig * gg;
    h = og * tanhf_(c);
  }
  h_out[(size_t)bn * 16 + k] = h;
}

// ---------------------------------------------------------------------------
// K2/K4/K6: fused d1(relu)+d2(relu), causal dilated 1x3 over T.
// Pure streaming, no LDS/barriers (R5-proven). Recomputes d1 at 3 taps.
// ---------------------------------------------------------------------------
template <int CI, int CO, int DIL, bool FIRST>
__global__ __launch_bounds__(128) void d12_kernel(
    const float* __restrict__ xin,
    const float* __restrict__ pw, const float* __restrict__ pb,
    const float* __restrict__ w1,  // [CO][CI][3]
    const float* __restrict__ w2,  // [CO][CO][3]
    float* __restrict__ out, int b0) {
  const int t = threadIdx.x;  // 128 threads
  const int n = blockIdx.x, by = blockIdx.y;

  float r1[3][CO];
#pragma unroll
  for (int u = 0; u < 3; u++)
#pragma unroll
    for (int co = 0; co < CO; co++) r1[u][co] = 0.f;

  if constexpr (FIRST) {
    const int b = b0 + by;
    const float4* xp = (const float4*)xin + ((size_t)b * N + n) * T;
    float px[5][4];
#pragma unroll
    for (int v = 0; v < 5; v++) {
      int idx = t - v * DIL;
      float4 xr = xp[idx < 0 ? 0 : idx];
      bool ok = idx >= 0;
      px[v][0] = ok ? pb[0] + pw[0] * xr.x + pw[1] * xr.y + pw[2] * xr.z + pw[3] * xr.w : 0.f;
      px[v][1] = ok ? pb[1] + pw[4] * xr.x + pw[5] * xr.y + pw[6] * xr.z + pw[7] * xr.w : 0.f;
      px[v][2] = ok ? pb[2] + pw[8] * xr.x + pw[9] * xr.y + pw[10] * xr.z + pw[11] * xr.w : 0.f;
      px[v][3] = ok ? pb[3] + pw[12] * xr.x + pw[13] * xr.y + pw[14] * xr.z + pw[15] * xr.w : 0.f;
    }
#pragma unroll
    for (int ci = 0; ci < CI; ci++) {
#pragma unroll
      for (int j = 0; j < 3; j++) {
#pragma unroll
        for (int co = 0; co < CO; co++) {
          float w = w1[(co * CI + ci) * 3 + j];
#pragma unroll
          for (int u = 0; u < 3; u++) r1[u][co] += w * px[u + 2 - j][ci];
        }
      }
    }
  } else {
#pragma unroll
    for (int ci = 0; ci < CI; ci++) {
      const float* xp = xin + (((size_t)by * CI + ci) * N + n) * T;
      float xt[5];
#pragma unroll
      for (int v = 0; v < 5; v++) {
        int idx = t - v * DIL;
        float xv = xp[idx < 0 ? 0 : idx];
        xt[v] = (idx >= 0) ? xv : 0.f;
      }
#pragma unroll
      for (int j = 0; j < 3; j++) {
#pragma unroll
        for (int co = 0; co < CO; co++) {
          float w = w1[(co * CI + ci) * 3 + j];
#pragma unroll
          for (int u = 0; u < 3; u++) r1[u][co] += w * xt[u + 2 - j];
        }
      }
    }
  }

#pragma unroll
  for (int u = 0; u < 3; u++)
#pragma unroll
    for (int co = 0; co < CO; co++) r1[u][co] = fmaxf(r1[u][co], 0.f);

  float acc[CO];
#pragma unroll
  for (int co = 0; co < CO; co++) acc[co] = 0.f;
#pragma unroll
  for (int cm = 0; cm < CO; cm++) {
#pragma unroll
    for (int j = 0; j < 3; j++) {
#pragma unroll
      for (int co = 0; co < CO; co++) {
        float w = w2[(co * CO + cm) * 3 + j];
        acc[co] += w * r1[2 - j][cm];
      }
    }
  }
#pragma unroll
  for (int co = 0; co < CO; co++)
    out[(((size_t)by * CO + co) * N + n) * T + t] = fmaxf(acc[co], 0.f);
}

// ---------------------------------------------------------------------------
// K3/K5/K7: cross-stock 11x1 conv over N + residual + relus.
// NEW: block = (t-tile of TT, b). The full n-extent of the input tile lives
// in LDS, so every input byte is fetched from global exactly ONCE (the old
// per-(b,n)-block version re-fetched the 11-row halo ~11x => 605 MB/dispatch).
// Residual rows are read directly from global (no reuse => no LDS).
// FUSEC4: conv4 partials reduced over t-lanes (shfl, width=TT) then one
// atomicAdd per (o,n) per block into zero-init'd h4 (pre-relu sums).
// ---------------------------------------------------------------------------
template <int C, int CIR, int RESMODE, bool FUSEC4>
__global__ __launch_bounds__(256) void cc_kernel(
    const float* __restrict__ zin,    // chunk [Bc][C][N][T]
    const float* __restrict__ ccw,    // [C][C][11]
    const float* __restrict__ resin,  // RESMODE 0: x global; else chunk buffer
    const float* __restrict__ rw,     // [C][CIR] or null
    const float* __restrict__ pw, const float* __restrict__ pb,
    float* __restrict__ out,          // chunk [Bc][C][N][T] or null
    const float* __restrict__ w4,     // [16][16][T] or null
    float* __restrict__ h4,           // [B][16][N] accum (pre-relu) or null
    int b0) {
  constexpr int TT = 8;                   // t-tile width
  constexpr int NS = 256 / TT;            // 32 n-lanes
  __shared__ float zs[C * N * TT];        // [ci][n][tl]
  __shared__ float w4s[FUSEC4 ? 16 * 16 * TT : 1];

  const int tid = threadIdx.x;
  const int tl = tid & (TT - 1);
  const int ns = tid / TT;                // 0..31
  const int tt = blockIdx.x, by = blockIdx.y;
  const int b = b0 + by;
  const int t0 = tt * TT;

  // Stage input tile: float4 loads, each global byte touched once.
  {
    const int nv = C * N * (TT / 4);      // float4 count
    for (int i = tid; i < nv; i += 256) {
      int ci = i / (N * 2), r = i % (N * 2);
      int nn = r >> 1, q = (r & 1) * 4;
      float4 v = *(const float4*)&zin[(((size_t)by * C + ci) * N + nn) * T + t0 + q];
      *(float4*)&zs[(ci * N + nn) * TT + q] = v;
    }
    if constexpr (FUSEC4) {
      for (int i = tid; i < 16 * 16 * (TT / 4); i += 256) {
        int oc = i >> 1, q = (i & 1) * 4;  // oc = o*16+ci
        float4 v = *(const float4*)&w4[(size_t)oc * T + t0 + q];
        *(float4*)&w4s[oc * TT + q] = v;
      }
    }
  }
  __syncthreads();

#pragma unroll 1
  for (int kk = 0; kk < (N + NS - 1) / NS; kk++) {
    const int n = ns + NS * kk;
    const bool valid = n < N;
    const int nc = valid ? n : 0;

    float acc[C];
#pragma unroll
    for (int co = 0; co < C; co++) acc[co] = 0.f;
#pragma unroll 1
    for (int dn = 0; dn < 11; dn++) {
      int nn = nc + dn - 5;
      bool ok = valid && (unsigned)nn < (unsigned)N;
      int nni = ok ? nn : 0;
#pragma unroll
      for (int ci = 0; ci < C; ci++) {
        float v = zs[(ci * N + nni) * TT + tl];
        v = ok ? v : 0.f;
#pragma unroll
        for (int co = 0; co < C; co++)
          acc[co] += ccw[(co * C + ci) * 11 + dn] * v;
      }
    }

    float y[C];
    if constexpr (RESMODE == 0) {
      float4 v = ((const float4*)resin)[(((size_t)b * N + nc) * T + t0 + tl) ];
      // note: resin is [B][N][T][4]; index above is element (b,n,t) of float4 array
      float xv[4];
#pragma unroll
      for (int j = 0; j < 4; j++)
        xv[j] = pb[j] + pw[j * 4 + 0] * v.x + pw[j * 4 + 1] * v.y +
                pw[j * 4 + 2] * v.z + pw[j * 4 + 3] * v.w;
#pragma unroll
      for (int co = 0; co < C; co++) {
        float rv = rw[co * 4 + 0] * xv[0] + rw[co * 4 + 1] * xv[1] +
                   rw[co * 4 + 2] * xv[2] + rw[co * 4 + 3] * xv[3];
        y[co] = fmaxf(rv + fmaxf(acc[co], 0.f), 0.f);
      }
    } else if constexpr (RESMODE == 1) {
      float rv[C];
#pragma unroll
      for (int co = 0; co < C; co++) rv[co] = 0.f;
#pragma unroll
      for (int ci = 0; ci < CIR; ci++) {
        float v = resin[(((size_t)by * CIR + ci) * N + nc) * T + t0 + tl];
#pragma unroll
        for (int co = 0; co < C; co++) rv[co] += rw[co * CIR + ci] * v;
      }
#pragma unroll
      for (int co = 0; co < C; co++)
        y[co] = fmaxf(rv[co] + fmaxf(acc[co], 0.f), 0.f);
    } else {
#pragma unroll
      for (int co = 0; co < C; co++) {
        float rv = resin[(((size_t)by * C + co) * N + nc) * T + t0 + tl];
        y[co] = fmaxf(rv + fmaxf(acc[co], 0.f), 0.f);
      }
    }

    if constexpr (!FUSEC4) {
      if (valid) {
#pragma unroll
        for (int co = 0; co < C; co++)
          out[(((size_t)by * C + co) * N + n) * T + t0 + tl] = y[co];
      }
    } else {
#pragma unroll
      for (int co = 0; co < C; co++) y[co] = valid ? y[co] : 0.f;
      float p[16];
#pragma unroll
      for (int o = 0; o < 16; o++) p[o] = 0.f;
#pragma unroll
      for (int ci = 0; ci < 16; ci++) {
        float yv = y[ci];
#pragma unroll
        for (int o = 0; o < 16; o++) p[o] += w4s[(o * 16 + ci) * TT + tl] * yv;
      }
#pragma unroll
      for (int o = 0; o < 16; o++) {
        float s = p[o];
        s += __shfl_down(s, 4, TT);
        s += __shfl_down(s, 2, TT);
        s += __shfl_down(s, 1, TT);
        p[o] = s;
      }
      if (tl == 0 && valid) {
#pragma unroll
        for (int o = 0; o < 16; o++)
          atomicAdd(&h4[((size_t)b * 16 + o) * N + n], p[o]);
      }
    }
  }
}

// ---------------------------------------------------------------------------
// K8: logits (with torch's reshape scramble of h_last) + softmax over N.
// h4 holds pre-relu conv4 sums -> relu applied here.
// ---------------------------------------------------------------------------
__global__ __launch_bounds__(128) void final_kernel(
    const float* __restrict__ hl,  // [B*N][16]
    const float* __restrict__ h4,  // [B][16][N] (pre-relu)
    const float* __restrict__ ow,  // [32]
    const float* __restrict__ ob,  // [1]
    float* __restrict__ out) {     // [B][N]
  __shared__ float red[128];
  int b = blockIdx.x, n = threadIdx.x;  // 128 threads
  bool valid = n < N;
  float lv = 0.f;
  if (valid) {
    int idx = b * N + n;
    int sb = idx & (B - 1);
    int sn = idx >> 8;
    const float* h = &hl[((size_t)sb * N + sn) * 16];
    float a = ob[0];
#pragma unroll
    for (int k = 0; k < 16; k++) a += h[k] * ow[k];
#pragma unroll
    for (int c = 0; c < 16; c++)
      a += fmaxf(h4[((size_t)b * 16 + c) * N + n], 0.f) * ow[16 + c];
    lv = a;
  }
  red[n] = valid ? lv : -1e30f;
  __syncthreads();
  for (int off = 64; off > 0; off >>= 1) {
    if (n < off) red[n] = fmaxf(red[n], red[n + off]);
    __syncthreads();
  }
  float m = red[0];
  __syncthreads();
  float e = valid ? __expf(lv - m) : 0.f;
  red[n] = e;
  __syncthreads();
  for (int off = 64; off > 0; off >>= 1) {
    if (n < off) red[n] += red[n + off];
    __syncthreads();
  }
  float s = red[0];
  if (valid) out[(size_t)b * N + n] = e / s;
}

// ---------------------------------------------------------------------------
// Launch. Conv pipeline chunked over B to fit whatever ws_size we're given.
// ---------------------------------------------------------------------------
extern "C" void kernel_launch(void* const* d_in, const int* in_sizes, int n_in,
                              void* d_out, int out_size, void* d_ws, size_t ws_size,
                              hipStream_t stream) {
  const float* x    = (const float*)d_in[0];
  const float* pw   = (const float*)d_in[1];
  const float* pb   = (const float*)d_in[2];
  const float* w_ih = (const float*)d_in[3];
  const float* w_hh = (const float*)d_in[4];
  const float* b_ih = (const float*)d_in[5];
  const float* b_hh = (const float*)d_in[6];
  const float* t1d1 = (const float*)d_in[7];
  const float* t1d2 = (const float*)d_in[8];
  const float* t1c  = (const float*)d_in[9];
  const float* t1r  = (const float*)d_in[10];
  const float* t2d1 = (const float*)d_in[11];
  const float* t2d2 = (const float*)d_in[12];
  const float* t2c  = (const float*)d_in[13];
  const float* t2r  = (const float*)d_in[14];
  const float* t3d1 = (const float*)d_in[15];
  const float* t3d2 = (const float*)d_in[16];
  const float* t3c  = (const float*)d_in[17];
  const float* w4   = (const float*)d_in[18];
  const float* ow   = (const float*)d_in[19];
  const float* ob   = (const float*)d_in[20];
  float* outp = (float*)d_out;

  const size_t NT = (size_t)N * T;          // 12928
  const size_t unit = 40 * NT;              // floats per chunked b
  const size_t fixed = 2 * (size_t)B * N * 16;

  int Bc = 4;
  const int cands[7] = {256, 128, 64, 32, 16, 8, 4};
  for (int i = 0; i < 7; i++) {
    if ((cands[i] * unit + fixed) * sizeof(float) <= ws_size) { Bc = cands[i]; break; }
  }

  float* ws = (float*)d_ws;
  float* hl = ws;                      // [B*N][16]
  float* h4 = hl + (size_t)B * N * 16; // [B][16][N]
  float* H1 = h4 + (size_t)B * 16 * N; // [Bc][8][N][T]
  float* Tb = H1 + (size_t)Bc * 8 * NT;   // [Bc][16][N][T]
  float* H2 = Tb + (size_t)Bc * 16 * NT;  // [Bc][16][N][T]

  hipMemsetAsync(h4, 0, (size_t)B * 16 * N * sizeof(float), stream);

  lstm_kernel<<<(B * N) / 16, 256, 0, stream>>>(x, pw, pb, w_ih, w_hh, b_ih,
                                                b_hh, hl);

  dim3 g(N, Bc);
  dim3 gcc(T / 8, Bc);
  for (int b0 = 0; b0 < B; b0 += Bc) {
    d12_kernel<4, 8, 1, true>
        <<<g, 128, 0, stream>>>(x, pw, pb, t1d1, t1d2, Tb, b0);
    cc_kernel<8, 4, 0, false><<<gcc, 256, 0, stream>>>(
        Tb, t1c, x, t1r, pw, pb, H1, nullptr, nullptr, b0);

    d12_kernel<8, 16, 2, false>
        <<<g, 128, 0, stream>>>(H1, pw, pb, t2d1, t2d2, Tb, b0);
    cc_kernel<16, 8, 1, false><<<gcc, 256, 0, stream>>>(
        Tb, t2c, H1, t2r, pw, pb, H2, nullptr, nullptr, b0);

    d12_kernel<16, 16, 4, false>
        <<<g, 128, 0, stream>>>(H2, pw, pb, t3d1, t3d2, Tb, b0);
    cc_kernel<16, 16, 2, true><<<gcc, 256, 0, stream>>>(
        Tb, t3c, H2, nullptr, pw, pb, nullptr, w4, h4, b0);
  }

  final_kernel<<<B, 128, 0, stream>>>(hl, h4, ow, ob, outp);
}

// Round 7
// 1838.373 us; speedup vs baseline: 2.0520x; 2.0520x over previous
//
#include <hip/hip_runtime.h>
#include <hip/hip_bf16.h>

// ---------------------------------------------------------------------------
// Problem constants (reference: B,N,T,P,H = 256,101,128,4,16)
// ---------------------------------------------------------------------------
constexpr int B = 256;
constexpr int N = 101;
constexpr int T = 128;

typedef float vf2 __attribute__((ext_vector_type(2)));

__device__ __forceinline__ float frcp(float x) { return __builtin_amdgcn_rcpf(x); }
__device__ __forceinline__ float sigmoidf_(float x) { return frcp(1.f + __expf(-x)); }
// tanh(x) = 2*sigmoid(2x) - 1  (safe at large |x|)
__device__ __forceinline__ float tanhf_(float x) { return 2.f * frcp(1.f + __expf(-2.f * x)) - 1.f; }

// XCD-aware n-swizzle: linear block id L -> n such that each XCD (L%8,
// assuming round-robin dispatch by linear id) owns a contiguous n-segment
// per b. Segments: 13,13,13,13,13,12,12,12 (sum=101). Bijection on [0,101).
// If the dispatch heuristic is wrong this only costs locality, not
// correctness.
__device__ __forceinline__ int swz_n(int L) {
  int q = L & 7, r = L >> 3;
  return q * 13 - (q > 5 ? (q - 5) : 0) + r;
}

// ---------------------------------------------------------------------------
// K1: LSTM, 16 lanes per pair of (b,n) rows (lane = hidden unit, 2 rows
// packed in float2 -> v_pk_fma_f32). Weights in VGPRs, h broadcast via shfl.
// h_out: [B*N][16]
// ---------------------------------------------------------------------------
__global__ __launch_bounds__(256) void lstm_kernel(
    const float* __restrict__ x,     // [B][N][T][4]
    const float* __restrict__ pw,    // [4][4]
    const float* __restrict__ pb,    // [4]
    const float* __restrict__ w_ih,  // [64][4]
    const float* __restrict__ w_hh,  // [64][16]
    const float* __restrict__ b_ih,  // [64]
    const float* __restrict__ b_hh,  // [64]
    float* __restrict__ h_out) {
  const int tid = threadIdx.x;
  const int lane = tid & 63;
  const int sub = lane >> 4;   // row-pair within wave (0..3)
  const int k = lane & 15;     // hidden unit owned by this lane
  const int wave = tid >> 6;   // wave within block (0..3)
  const int row = blockIdx.x * 32 + wave * 8 + sub * 2;  // 808*32 = 25856

  float wih[4][4], whh[4][16], bias[4];
#pragma unroll
  for (int q = 0; q < 4; q++) {
    const int j = q * 16 + k;  // gate order i,f,g,o
    bias[q] = b_ih[j] + b_hh[j];
#pragma unroll
    for (int jj = 0; jj < 4; jj++) wih[q][jj] = w_ih[j * 4 + jj];
#pragma unroll
    for (int m = 0; m < 16; m++) whh[q][m] = w_hh[j * 16 + m];
  }
  float pwr[16], pbr[4];
#pragma unroll
  for (int i = 0; i < 16; i++) pwr[i] = pw[i];
#pragma unroll
  for (int i = 0; i < 4; i++) pbr[i] = pb[i];

  vf2 h = {0.f, 0.f}, c = {0.f, 0.f};
  const float4* xpA = (const float4*)x + (size_t)row * T;
  const float4* xpB = xpA + T;
  const int base = sub * 16;

#pragma unroll 1
  for (int t = 0; t < T; t++) {
    float4 xa = xpA[t];
    float4 xb = xpB[t];
    vf2 xv[4];
#pragma unroll
    for (int j = 0; j < 4; j++) {
      vf2 v = {pbr[j], pbr[j]};
      v += pwr[j * 4 + 0] * (vf2){xa.x, xb.x};
      v += pwr[j * 4 + 1] * (vf2){xa.y, xb.y};
      v += pwr[j * 4 + 2] * (vf2){xa.z, xb.z};
      v += pwr[j * 4 + 3] * (vf2){xa.w, xb.w};
      xv[j] = v;
    }
    vf2 a0 = {bias[0], bias[0]}, a1 = {bias[1], bias[1]};
    vf2 a2 = {bias[2], bias[2]}, a3 = {bias[3], bias[3]};
#pragma unroll
    for (int j = 0; j < 4; j++) {
      a0 += wih[0][j] * xv[j];
      a1 += wih[1][j] * xv[j];
      a2 += wih[2][j] * xv[j];
      a3 += wih[3][j] * xv[j];
    }
#pragma unroll
    for (int m = 0; m < 16; m++) {
      vf2 hm;
      hm.x = __shfl(h.x, base + m, 64);
      hm.y = __shfl(h.y, base + m, 64);
      a0 += whh[0][m] * hm;
      a1 += whh[1][m] * hm;
      a2 += whh[2][m] * hm;
      a3 += whh[3][m] * hm;
    }
    vf2 ig, fg, gg, og, tc;
    ig.x = sigmoidf_(a0.x); ig.y = sigmoidf_(a0.y);
    fg.x = sigmoidf_(a1.x); fg.y = sigmoidf_(a1.y);
    gg.x = tanhf_(a2.x);    gg.y = tanhf_(a2.y);
    og.x = sigmoidf_(a3.x); og.y = sigmoidf_(a3.y);
    c = fg * c + ig * gg;
    tc.x = tanhf_(c.x);     tc.y = tanhf_(c.y);
    h = og * tc;
  }
  h_out[(size_t)row * 16 + k] = h.x;
  h_out[(size_t)(row + 1) * 16 + k] = h.y;
}

// ---------------------------------------------------------------------------
// K2/K4/K6: fused d1(relu)+d2(relu), causal dilated 1x3 over T.
// Pure streaming, no LDS/barriers (R5-proven). Recomputes d1 at 3 taps.
// n swizzled identically to cc so producer/consumer share an XCD's L2.
// ---------------------------------------------------------------------------
template <int CI, int CO, int DIL, bool FIRST>
__global__ __launch_bounds__(128) void d12_kernel(
    const float* __restrict__ xin,
    const float* __restrict__ pw, const float* __restrict__ pb,
    const float* __restrict__ w1,  // [CO][CI][3]
    const float* __restrict__ w2,  // [CO][CO][3]
    float* __restrict__ out, int b0) {
  const int t = threadIdx.x;  // 128 threads
  const int n = swz_n(blockIdx.x), by = blockIdx.y;

  float r1[3][CO];
#pragma unroll
  for (int u = 0; u < 3; u++)
#pragma unroll
    for (int co = 0; co < CO; co++) r1[u][co] = 0.f;

  if constexpr (FIRST) {
    const int b = b0 + by;
    const float4* xp = (const float4*)xin + ((size_t)b * N + n) * T;
    float px[5][4];
#pragma unroll
    for (int v = 0; v < 5; v++) {
      int idx = t - v * DIL;
      float4 xr = xp[idx < 0 ? 0 : idx];
      bool ok = idx >= 0;
      px[v][0] = ok ? pb[0] + pw[0] * xr.x + pw[1] * xr.y + pw[2] * xr.z + pw[3] * xr.w : 0.f;
      px[v][1] = ok ? pb[1] + pw[4] * xr.x + pw[5] * xr.y + pw[6] * xr.z + pw[7] * xr.w : 0.f;
      px[v][2] = ok ? pb[2] + pw[8] * xr.x + pw[9] * xr.y + pw[10] * xr.z + pw[11] * xr.w : 0.f;
      px[v][3] = ok ? pb[3] + pw[12] * xr.x + pw[13] * xr.y + pw[14] * xr.z + pw[15] * xr.w : 0.f;
    }
#pragma unroll
    for (int ci = 0; ci < CI; ci++) {
#pragma unroll
      for (int j = 0; j < 3; j++) {
#pragma unroll
        for (int co = 0; co < CO; co++) {
          float w = w1[(co * CI + ci) * 3 + j];
#pragma unroll
          for (int u = 0; u < 3; u++) r1[u][co] += w * px[u + 2 - j][ci];
        }
      }
    }
  } else {
#pragma unroll
    for (int ci = 0; ci < CI; ci++) {
      const float* xp = xin + (((size_t)by * CI + ci) * N + n) * T;
      float xt[5];
#pragma unroll
      for (int v = 0; v < 5; v++) {
        int idx = t - v * DIL;
        float xv = xp[idx < 0 ? 0 : idx];
        xt[v] = (idx >= 0) ? xv : 0.f;
      }
#pragma unroll
      for (int j = 0; j < 3; j++) {
#pragma unroll
        for (int co = 0; co < CO; co++) {
          float w = w1[(co * CI + ci) * 3 + j];
#pragma unroll
          for (int u = 0; u < 3; u++) r1[u][co] += w * xt[u + 2 - j];
        }
      }
    }
  }

#pragma unroll
  for (int u = 0; u < 3; u++)
#pragma unroll
    for (int co = 0; co < CO; co++) r1[u][co] = fmaxf(r1[u][co], 0.f);

  float acc[CO];
#pragma unroll
  for (int co = 0; co < CO; co++) acc[co] = 0.f;
#pragma unroll
  for (int cm = 0; cm < CO; cm++) {
#pragma unroll
    for (int j = 0; j < 3; j++) {
#pragma unroll
      for (int co = 0; co < CO; co++) {
        float w = w2[(co * CO + cm) * 3 + j];
        acc[co] += w * r1[2 - j][cm];
      }
    }
  }
#pragma unroll
  for (int co = 0; co < CO; co++)
    out[(((size_t)by * CO + co) * N + n) * T + t] = fmaxf(acc[co], 0.f);
}

// ---------------------------------------------------------------------------
// K3/K5/K7: cross-stock 11x1 conv over N + residual + relus. (R5-proven
// streaming version + XCD n-swizzle so the 11-row halo stays in one L2.)
// RESMODE: 0 = residual from raw x via proj + 1x1 rw (stage 1)
//          1 = residual via 1x1 rw from chunk buffer (stage 2)
//          2 = identity residual from chunk buffer (stage 3)
// FUSEC4: fuse conv4 (kernel (1,T)) + relu, write h4 [B][16][N] (global b).
// ---------------------------------------------------------------------------
template <int C, int CIR, int RESMODE, bool FUSEC4>
__global__ __launch_bounds__(128) void cc_kernel(
    const float* __restrict__ zin,    // chunk [Bc][C][N][T]
    const float* __restrict__ ccw,    // [C][C][11]
    const float* __restrict__ resin,  // RESMODE 0: x global; else chunk buffer
    const float* __restrict__ rw,     // [C][CIR] or null
    const float* __restrict__ pw, const float* __restrict__ pb,
    float* __restrict__ out,          // chunk [Bc][C][N][T] or null
    const float* __restrict__ w4,     // [16][16][T] or null
    float* __restrict__ h4,           // [B][16][N] or null
    int b0) {
  const int t = threadIdx.x;  // 128 threads
  const int n = swz_n(blockIdx.x), by = blockIdx.y;
  const int b = b0 + by;

  float acc[C];
#pragma unroll
  for (int co = 0; co < C; co++) acc[co] = 0.f;
  for (int dn = 0; dn < 11; dn++) {
    int nn = n + dn - 5;
    if ((unsigned)nn >= (unsigned)N) continue;  // zero-pad over N (block-uniform)
#pragma unroll
    for (int ci = 0; ci < C; ci++) {
      float v = zin[(((size_t)by * C + ci) * N + nn) * T + t];
#pragma unroll
      for (int co = 0; co < C; co++)
        acc[co] += ccw[(co * C + ci) * 11 + dn] * v;
    }
  }

  float y[C];
  if constexpr (RESMODE == 0) {
    float4 v = ((const float4*)resin)[((size_t)b * N + n) * T + t];
    float xv[4];
#pragma unroll
    for (int j = 0; j < 4; j++)
      xv[j] = pb[j] + pw[j * 4 + 0] * v.x + pw[j * 4 + 1] * v.y +
              pw[j * 4 + 2] * v.z + pw[j * 4 + 3] * v.w;
#pragma unroll
    for (int co = 0; co < C; co++) {
      float rv = rw[co * 4 + 0] * xv[0] + rw[co * 4 + 1] * xv[1] +
                 rw[co * 4 + 2] * xv[2] + rw[co * 4 + 3] * xv[3];
      y[co] = fmaxf(rv + fmaxf(acc[co], 0.f), 0.f);
    }
  } else if constexpr (RESMODE == 1) {
    float rv[C];
#pragma unroll
    for (int co = 0; co < C; co++) rv[co] = 0.f;
#pragma unroll
    for (int ci = 0; ci < CIR; ci++) {
      float v = resin[(((size_t)by * CIR + ci) * N + n) * T + t];
#pragma unroll
      for (int co = 0; co < C; co++) rv[co] += rw[co * CIR + ci] * v;
    }
#pragma unroll
    for (int co = 0; co < C; co++) y[co] = fmaxf(rv[co] + fmaxf(acc[co], 0.f), 0.f);
  } else {
#pragma unroll
    for (int co = 0; co < C; co++) {
      float rv = resin[(((size_t)by * C + co) * N + n) * T + t];
      y[co] = fmaxf(rv + fmaxf(acc[co], 0.f), 0.f);
    }
  }

  if constexpr (!FUSEC4) {
#pragma unroll
    for (int co = 0; co < C; co++)
      out[(((size_t)by * C + co) * N + n) * T + t] = y[co];
  } else {
    // conv4: h4[b][o][n] = relu(sum_{ci,t} w4[o][ci][t] * y[ci][t])
    float p[16];
#pragma unroll
    for (int o = 0; o < 16; o++) {
      float s = 0.f;
#pragma unroll
      for (int ci = 0; ci < 16; ci++) s += w4[(o * 16 + ci) * T + t] * y[ci];
      p[o] = s;
    }
    __shared__ float red[2][16];
#pragma unroll
    for (int o = 0; o < 16; o++) {
      float s = p[o];
#pragma unroll
      for (int off = 32; off > 0; off >>= 1) s += __shfl_down(s, off);
      p[o] = s;
    }
    int wv = t >> 6, lane = t & 63;
    if (lane == 0) {
#pragma unroll
      for (int o = 0; o < 16; o++) red[wv][o] = p[o];
    }
    __syncthreads();
    if (t < 16) {
      float s = red[0][t] + red[1][t];
      h4[((size_t)b * 16 + t) * N + n] = fmaxf(s, 0.f);
    }
  }
}

// ---------------------------------------------------------------------------
// K8: logits (with torch's reshape scramble of h_last) + softmax over N
// ---------------------------------------------------------------------------
__global__ __launch_bounds__(128) void final_kernel(
    const float* __restrict__ hl,  // [B*N][16]
    const float* __restrict__ h4,  // [B][16][N]
    const float* __restrict__ ow,  // [32]
    const float* __restrict__ ob,  // [1]
    float* __restrict__ out) {     // [B][N]
  __shared__ float red[128];
  int b = blockIdx.x, n = threadIdx.x;  // 128 threads
  bool valid = n < N;
  float lv = 0.f;
  if (valid) {
    int idx = b * N + n;
    int sb = idx & (B - 1);
    int sn = idx >> 8;
    const float* h = &hl[((size_t)sb * N + sn) * 16];
    float a = ob[0];
#pragma unroll
    for (int k = 0; k < 16; k++) a += h[k] * ow[k];
#pragma unroll
    for (int c = 0; c < 16; c++) a += h4[((size_t)b * 16 + c) * N + n] * ow[16 + c];
    lv = a;
  }
  red[n] = valid ? lv : -1e30f;
  __syncthreads();
  for (int off = 64; off > 0; off >>= 1) {
    if (n < off) red[n] = fmaxf(red[n], red[n + off]);
    __syncthreads();
  }
  float m = red[0];
  __syncthreads();
  float e = valid ? __expf(lv - m) : 0.f;
  red[n] = e;
  __syncthreads();
  for (int off = 64; off > 0; off >>= 1) {
    if (n < off) red[n] += red[n + off];
    __syncthreads();
  }
  float s = red[0];
  if (valid) out[(size_t)b * N + n] = e / s;
}

// ---------------------------------------------------------------------------
// Launch. Conv pipeline chunked over B to fit whatever ws_size we're given.
// ---------------------------------------------------------------------------
extern "C" void kernel_launch(void* const* d_in, const int* in_sizes, int n_in,
                              void* d_out, int out_size, void* d_ws, size_t ws_size,
                              hipStream_t stream) {
  const float* x    = (const float*)d_in[0];
  const float* pw   = (const float*)d_in[1];
  const float* pb   = (const float*)d_in[2];
  const float* w_ih = (const float*)d_in[3];
  const float* w_hh = (const float*)d_in[4];
  const float* b_ih = (const float*)d_in[5];
  const float* b_hh = (const float*)d_in[6];
  const float* t1d1 = (const float*)d_in[7];
  const float* t1d2 = (const float*)d_in[8];
  const float* t1c  = (const float*)d_in[9];
  const float* t1r  = (const float*)d_in[10];
  const float* t2d1 = (const float*)d_in[11];
  const float* t2d2 = (const float*)d_in[12];
  const float* t2c  = (const float*)d_in[13];
  const float* t2r  = (const float*)d_in[14];
  const float* t3d1 = (const float*)d_in[15];
  const float* t3d2 = (const float*)d_in[16];
  const float* t3c  = (const float*)d_in[17];
  const float* w4   = (const float*)d_in[18];
  const float* ow   = (const float*)d_in[19];
  const float* ob   = (const float*)d_in[20];
  float* outp = (float*)d_out;

  const size_t NT = (size_t)N * T;          // 12928
  const size_t unit = 40 * NT;              // floats per chunked b
  const size_t fixed = 2 * (size_t)B * N * 16;

  int Bc = 4;
  const int cands[7] = {256, 128, 64, 32, 16, 8, 4};
  for (int i = 0; i < 7; i++) {
    if ((cands[i] * unit + fixed) * sizeof(float) <= ws_size) { Bc = cands[i]; break; }
  }

  float* ws = (float*)d_ws;
  float* hl = ws;                      // [B*N][16]
  float* h4 = hl + (size_t)B * N * 16; // [B][16][N]
  float* H1 = h4 + (size_t)B * 16 * N; // [Bc][8][N][T]
  float* Tb = H1 + (size_t)Bc * 8 * NT;   // [Bc][16][N][T]
  float* H2 = Tb + (size_t)Bc * 16 * NT;  // [Bc][16][N][T]

  lstm_kernel<<<(B * N) / 32, 256, 0, stream>>>(x, pw, pb, w_ih, w_hh, b_ih,
                                                b_hh, hl);

  dim3 g(N, Bc);
  for (int b0 = 0; b0 < B; b0 += Bc) {
    d12_kernel<4, 8, 1, true>
        <<<g, 128, 0, stream>>>(x, pw, pb, t1d1, t1d2, Tb, b0);
    cc_kernel<8, 4, 0, false><<<g, 128, 0, stream>>>(
        Tb, t1c, x, t1r, pw, pb, H1, nullptr, nullptr, b0);

    d12_kernel<8, 16, 2, false>
        <<<g, 128, 0, stream>>>(H1, pw, pb, t2d1, t2d2, Tb, b0);
    cc_kernel<16, 8, 1, false><<<g, 128, 0, stream>>>(
        Tb, t2c, H1, t2r, pw, pb, H2, nullptr, nullptr, b0);

    d12_kernel<16, 16, 4, false>
        <<<g, 128, 0, stream>>>(H2, pw, pb, t3d1, t3d2, Tb, b0);
    cc_kernel<16, 16, 2, true><<<g, 128, 0, stream>>>(
        Tb, t3c, H2, nullptr, pw, pb, nullptr, w4, h4, b0);
  }

  final_kernel<<<B, 128, 0, stream>>>(hl, h4, ow, ob, outp);
}